// Round 15
// baseline (253.634 us; speedup 1.0000x reference)
//
#include <hip/hip_runtime.h>
#include <cmath>

#define BS   2
#define SEQ  2048
#define DM   1024
#define NH   16
#define HD   64
#define D3   3072
#define MROWS 4096
#define KVBLK 64
#define QBLK  128
#define NTILES (SEQ / KVBLK)   // 32
#define NCHUNK 2               // split-KV factor
#define CTILES (NTILES / NCHUNK)

// log2(e)/8: folds softmax scale and exp->exp2 conversion into one FMA
#define CSC 0.18033688011112042f

typedef _Float16 f16;
typedef __attribute__((ext_vector_type(4))) _Float16 half4;
typedef __attribute__((ext_vector_type(8))) _Float16 half8;
typedef __attribute__((ext_vector_type(4))) float f32x4;
typedef unsigned int u32;
typedef __attribute__((ext_vector_type(2))) u32 u32x2;
typedef __attribute__((ext_vector_type(4))) u32 u32x4;

__device__ __forceinline__ void async_cp16(const void* g, void* s) {
    __builtin_amdgcn_global_load_lds(
        (const __attribute__((address_space(1))) u32*)g,
        (__attribute__((address_space(3))) u32*)s, 16, 0, 0);
}

// ---------------------------------------------------------------------------
// Conversion passes
// ---------------------------------------------------------------------------
__global__ __launch_bounds__(256) void conv_concat_kernel(
    const float* __restrict__ q, const float* __restrict__ k,
    const float* __restrict__ v, f16* __restrict__ out)
{
    const int seg = blockIdx.x;            // 0..2
    const int row = blockIdx.y;            // 0..4095
    const int c   = threadIdx.x * 4;
    const float* src = (seg == 0 ? q : (seg == 1 ? k : v)) + (size_t)row * DM + c;
    float4 x = *(const float4*)src;
    half4 h = {(f16)x.x, (f16)x.y, (f16)x.z, (f16)x.w};
    *(half4*)&out[(size_t)row * D3 + seg * DM + c] = h;
}

__global__ __launch_bounds__(256) void conv_plain_kernel(
    const float* __restrict__ src, f16* __restrict__ dst, int n4)
{
    int i = blockIdx.x * 256 + threadIdx.x;
    const int stride = gridDim.x * 256;
    for (; i < n4; i += stride) {
        float4 x = *(const float4*)&src[(size_t)i * 4];
        half4 h = {(f16)x.x, (f16)x.y, (f16)x.z, (f16)x.w};
        *(half4*)&dst[(size_t)i * 4] = h;
    }
}

// ---------------------------------------------------------------------------
// 8-phase 256x256 fp16 MFMA GEMM (r13 exact: proven (r>>1)&3 swizzle)
// ---------------------------------------------------------------------------
#define SWZ4(r) (((r) >> 1) & 3)

template<int KDIM, int NDIM>
__global__ __launch_bounds__(512, 2) void gemm8p_f16_kernel(
    const f16* __restrict__ A, const f16* __restrict__ W,
    const float* __restrict__ bias, f16* __restrict__ Cout)
{
    __shared__ f16 lds[65536];   // 128 KB

    const int tid  = threadIdx.x;
    const int lane = tid & 63;
    const int wave = tid >> 6;        // 0..7
    const int l15  = lane & 15;
    const int lg   = lane >> 4;
    const int wm   = wave >> 2;       // 0..1 (M half)
    const int wn   = wave & 3;        // 0..3 (N quarter)

    const int cpx = gridDim.x >> 3;   // grid % 8 == 0 (192)
    const int lid = (blockIdx.x & 7) * cpx + (blockIdx.x >> 3);
    const int NTC = NDIM / 256;
    const int tM0 = (lid / NTC) * 256;
    const int tN0 = (lid % NTC) * 256;

    const int rr  = wave * 16 + (lane >> 2);     // 0..127
    const int cs  = (lane & 3) ^ SWZ4(rr);       // pre-swizzled source chunk
    const f16* gA = A + (size_t)(tM0 + rr) * KDIM + cs * 8;
    const f16* gW = W + (size_t)(tN0 + rr) * KDIM + cs * 8;
    const int sbase = wave * 512;                // wave-uniform LDS stage base

    f32x4 acc[8][4];
#pragma unroll
    for (int i = 0; i < 8; ++i)
#pragma unroll
        for (int j = 0; j < 4; ++j) acc[i][j] = (f32x4){0.f, 0.f, 0.f, 0.f};

    const int fch = lg ^ SWZ4(l15);
    const int aro = (wm * 128 + l15) * 32 + fch * 8;            // + mi*512
    const int bro = 32768 + (wn * 64 + l15) * 32 + fch * 8;     // + ni*512

    constexpr int NT = KDIM / 64;    // 48 K-tiles

#define STAGE_A(S, KS, KT) do {                                               \
    const f16* s_ = gA + (size_t)(KT) * 64 + (KS) * 32;                       \
    f16* d_ = &lds[(S) * 16384 + (KS) * 8192 + sbase];                        \
    async_cp16(s_, d_);                                                       \
    async_cp16(s_ + (size_t)128 * KDIM, d_ + 4096);                           \
} while (0)

#define STAGE_B(S, KS, KT) do {                                               \
    const f16* s_ = gW + (size_t)(KT) * 64 + (KS) * 32;                       \
    f16* d_ = &lds[32768 + (S) * 16384 + (KS) * 8192 + sbase];                \
    async_cp16(s_, d_);                                                       \
    async_cp16(s_ + (size_t)128 * KDIM, d_ + 4096);                           \
} while (0)

#define PHASE(S, KS, MH, VMEND, STAGE_STMT) do {                              \
    const int pb_ = (S) * 16384 + (KS) * 8192;                                \
    half8 af[4];                                                              \
    _Pragma("unroll")                                                         \
    for (int mi = 0; mi < 4; ++mi)                                            \
        af[mi] = *(half8*)&lds[pb_ + aro + ((MH) * 4 + mi) * 512];            \
    if ((MH) == 0) {                                                          \
        _Pragma("unroll")                                                     \
        for (int ni = 0; ni < 4; ++ni)                                        \
            wf[ni] = *(half8*)&lds[pb_ + bro + ni * 512];                     \
    }                                                                         \
    STAGE_STMT;                                                               \
    __builtin_amdgcn_s_barrier();                                             \
    asm volatile("s_waitcnt lgkmcnt(0)" ::: "memory");                        \
    __builtin_amdgcn_sched_barrier(0);                                        \
    __builtin_amdgcn_s_setprio(1);                                            \
    _Pragma("unroll")                                                         \
    for (int mi = 0; mi < 4; ++mi)                                            \
        _Pragma("unroll")                                                     \
        for (int ni = 0; ni < 4; ++ni)                                        \
            acc[(MH) * 4 + mi][ni] = __builtin_amdgcn_mfma_f32_16x16x32_f16(  \
                af[mi], wf[ni], acc[(MH) * 4 + mi][ni], 0, 0, 0);             \
    __builtin_amdgcn_s_setprio(0);                                            \
    __builtin_amdgcn_sched_barrier(0);                                        \
    if (VMEND) {                                                              \
        asm volatile("s_waitcnt vmcnt(8)" ::: "memory");                      \
        __builtin_amdgcn_sched_barrier(0);                                    \
    }                                                                         \
    __builtin_amdgcn_s_barrier();                                             \
} while (0)

    // prologue: issue order defines the vmcnt FIFO (12 loads)
    STAGE_A(0, 0, 0); STAGE_B(0, 0, 0);
    STAGE_A(0, 1, 0); STAGE_B(0, 1, 0);
    STAGE_A(1, 0, 1); STAGE_B(1, 0, 1);
    asm volatile("s_waitcnt vmcnt(8)" ::: "memory");
    __builtin_amdgcn_s_barrier();

    half8 wf[4];
    for (int it = 0; it < NT / 2; ++it) {
        const int t   = 2 * it;
        const int t1c = t + 1;
        const int t2c = (t + 2 < NT) ? t + 2 : NT - 1;
        const int t3c = (t + 3 < NT) ? t + 3 : NT - 1;
        PHASE(0, 0, 0, false, STAGE_A(1, 1, t1c));
        PHASE(0, 0, 1, true,  STAGE_B(1, 1, t1c));
        PHASE(0, 1, 0, false, STAGE_A(0, 0, t2c));
        PHASE(0, 1, 1, true,  STAGE_B(0, 0, t2c));
        PHASE(1, 0, 0, false, STAGE_A(0, 1, t2c));
        PHASE(1, 0, 1, true,  STAGE_B(0, 1, t2c));
        PHASE(1, 1, 0, false, STAGE_A(1, 0, t3c));
        PHASE(1, 1, 1, true,  STAGE_B(1, 0, t3c));
    }

#undef PHASE
#undef STAGE_A
#undef STAGE_B

    float bv[4];
#pragma unroll
    for (int ni = 0; ni < 4; ++ni) bv[ni] = bias[tN0 + wn * 64 + ni * 16 + l15];

#pragma unroll
    for (int mi = 0; mi < 8; ++mi)
#pragma unroll
        for (int ni = 0; ni < 4; ++ni)
#pragma unroll
            for (int r = 0; r < 4; ++r) {
                const int m   = tM0 + wm * 128 + mi * 16 + lg * 4 + r;
                const int col = tN0 + wn * 64 + ni * 16 + l15;
                Cout[(size_t)m * NDIM + col] = (f16)(acc[mi][ni][r] + bv[ni]);
            }
}

// ---------------------------------------------------------------------------
// Output-projection GEMM (round-10: 64x128 tile, 2 waves, grid 512)
// ---------------------------------------------------------------------------
__global__ __launch_bounds__(128) void gemm_out_kernel(
    const f16* __restrict__ A, const f16* __restrict__ W,
    const float* __restrict__ bias, float* __restrict__ Cout)
{
    constexpr int KDIM = DM, NDIM = DM;
    __shared__ f16 As[64 * 32];     // 4 KB
    __shared__ f16 Ws[128 * 32];    // 8 KB

    const int tid  = threadIdx.x;   // 0..127
    const int lane = tid & 63;
    const int wave = tid >> 6;      // 0..1
    const int l15  = lane & 15;
    const int lg   = lane >> 4;

    const int cpx = gridDim.x >> 3;             // 512/8 = 64
    const int lid = (blockIdx.x & 7) * cpx + (blockIdx.x >> 3);
    const int NT2 = NDIM / 128;                 // 8
    const int tM0 = (lid / NT2) * 64;
    const int tN0 = (lid % NT2) * 128;

    const int srow = lane >> 2;                 // 0..15
    const int sch  = lane & 3;
    const int ssc  = sch ^ ((srow >> 1) & 3);

    const f16* gA0 = A + (size_t)(tM0 + wave * 32      + srow) * KDIM + ssc * 8;
    const f16* gA1 = A + (size_t)(tM0 + wave * 32 + 16 + srow) * KDIM + ssc * 8;
    const f16* gW0 = W + (size_t)(tN0 + wave * 64      + srow) * KDIM + ssc * 8;
    const f16* gW1 = W + (size_t)(tN0 + wave * 64 + 16 + srow) * KDIM + ssc * 8;
    const f16* gW2 = W + (size_t)(tN0 + wave * 64 + 32 + srow) * KDIM + ssc * 8;
    const f16* gW3 = W + (size_t)(tN0 + wave * 64 + 48 + srow) * KDIM + ssc * 8;
    f16* lA0 = &As[(wave * 32)      * 32];
    f16* lA1 = &As[(wave * 32 + 16) * 32];
    f16* lW0 = &Ws[(wave * 64)      * 32];
    f16* lW1 = &Ws[(wave * 64 + 16) * 32];
    f16* lW2 = &Ws[(wave * 64 + 32) * 32];
    f16* lW3 = &Ws[(wave * 64 + 48) * 32];

    f32x4 acc[4][4];
#pragma unroll
    for (int i = 0; i < 4; ++i)
#pragma unroll
        for (int j = 0; j < 4; ++j) acc[i][j] = (f32x4){0.f, 0.f, 0.f, 0.f};

    const int fsw = (lg ^ ((l15 >> 1) & 3)) * 8;
    int aoff[4], woff[4];
#pragma unroll
    for (int mi = 0; mi < 4; ++mi) aoff[mi] = (mi * 16 + l15) * 32 + fsw;
#pragma unroll
    for (int ni = 0; ni < 4; ++ni) woff[ni] = (wave * 64 + ni * 16 + l15) * 32 + fsw;

    for (int k0 = 0; k0 < KDIM; k0 += 32) {
        __syncthreads();
        async_cp16(gA0 + k0, lA0);
        async_cp16(gA1 + k0, lA1);
        async_cp16(gW0 + k0, lW0);
        async_cp16(gW1 + k0, lW1);
        async_cp16(gW2 + k0, lW2);
        async_cp16(gW3 + k0, lW3);
        __syncthreads();

        half8 af[4], wf[4];
#pragma unroll
        for (int mi = 0; mi < 4; ++mi) af[mi] = *(half8*)&As[aoff[mi]];
#pragma unroll
        for (int ni = 0; ni < 4; ++ni) wf[ni] = *(half8*)&Ws[woff[ni]];
#pragma unroll
        for (int mi = 0; mi < 4; ++mi)
#pragma unroll
            for (int ni = 0; ni < 4; ++ni)
                acc[mi][ni] = __builtin_amdgcn_mfma_f32_16x16x32_f16(
                    af[mi], wf[ni], acc[mi][ni], 0, 0, 0);
    }

    float bv[4];
#pragma unroll
    for (int ni = 0; ni < 4; ++ni) bv[ni] = bias[tN0 + wave * 64 + ni * 16 + l15];

#pragma unroll
    for (int mi = 0; mi < 4; ++mi)
#pragma unroll
        for (int ni = 0; ni < 4; ++ni)
#pragma unroll
            for (int r = 0; r < 4; ++r) {
                const int m   = tM0 + mi * 16 + lg * 4 + r;
                const int col = tN0 + wave * 64 + ni * 16 + l15;
                Cout[(size_t)m * NDIM + col] = acc[mi][ni][r] + bv[ni];
            }
}

// ---------------------------------------------------------------------------
// fp16 MFMA flash attention, swapped-operand, split-KV x2, NO P-LDS:
// P re-layout (C-layout -> B-fragment) done fully in-register via 3x
// shfl_xor (16/32/48) within each 4-lane lg group. Mapping (derived +
// spot-verified): lane(lg,l15) needs for (ks2,u) source lane (2lg+u)&3,
// ct' = 2ks2+(lg>>1); send-sets q02/q13 chosen by receiver's lg>>1.
// LDS 32 KB (was 48) -> under the 40KB residency line -> 4 blocks/CU.
// ---------------------------------------------------------------------------

#define V_STORE(VtN, va, vb) do {                                             \
    u32x4 aw_ = __builtin_bit_cast(u32x4, va);                                \
    u32x4 bw_ = __builtin_bit_cast(u32x4, vb);                                \
    _Pragma("unroll")                                                         \
    for (int wd_ = 0; wd_ < 4; ++wd_) {                                       \
        u32 lo_ = __builtin_amdgcn_perm(bw_[wd_], aw_[wd_], 0x05040100u);     \
        u32 hi_ = __builtin_amdgcn_perm(bw_[wd_], aw_[wd_], 0x07060302u);     \
        const int dl_ = vd0 + 2 * wd_;                                        \
        const int dh_ = dl_ + 1;                                              \
        *(u32*)&VtN[dl_ * KVBLK + (((vp >> 2) ^ (dl_ & 7) ^ (dl_ >> 3)) * 8)  \
                    + 2 * (vp & 3)] = lo_;                                    \
        *(u32*)&VtN[dh_ * KVBLK + (((vp >> 2) ^ (dh_ & 7) ^ (dh_ >> 3)) * 8)  \
                    + 2 * (vp & 3)] = hi_;                                    \
    }                                                                         \
} while (0)

#define ATTN_STEP(KhC, VtC, KhN, VtN, TT, PF) do {                            \
    half8 va_ = {}, vb_ = {};                                                 \
    if (PF) {                                                                 \
        const size_t nro_ = (size_t)((TT) + 1) * KVBLK;                       \
        async_cp16(kxsrc + (nro_ + wave * 16 +     krow_l) * D3,              \
                   &KhN[(wave * 16) * HD]);                                   \
        async_cp16(kxsrc + (nro_ + wave * 16 + 8 + krow_l) * D3,              \
                   &KhN[(wave * 16 + 8) * HD]);                               \
        va_ = *(const half8*)(vsrc0 + nro_ * D3);                             \
        vb_ = *(const half8*)(vsrc0 + nro_ * D3 + D3);                        \
    }                                                                         \
    f32x4 sc[2][4];                                                           \
    _Pragma("unroll")                                                         \
    for (int rt = 0; rt < 2; ++rt)                                            \
        _Pragma("unroll")                                                     \
        for (int ct = 0; ct < 4; ++ct) sc[rt][ct] = (f32x4){0.f,0.f,0.f,0.f}; \
    __builtin_amdgcn_s_setprio(1);                                            \
    _Pragma("unroll")                                                         \
    for (int ct = 0; ct < 4; ++ct) {                                          \
        const int krow = ct * 16 + l15;                                       \
        _Pragma("unroll")                                                     \
        for (int ks = 0; ks < 2; ++ks) {                                      \
            half8 kf = *(half8*)&KhC[krow * HD +                              \
                                     (((ks * 4 + lg) ^ (krow & 7)) * 8)];     \
            _Pragma("unroll")                                                 \
            for (int rt = 0; rt < 2; ++rt)                                    \
                sc[rt][ct] = __builtin_amdgcn_mfma_f32_16x16x32_f16(          \
                    kf, qf[rt][ks], sc[rt][ct], 0, 0, 0);                     \
        }                                                                     \
    }                                                                         \
    __builtin_amdgcn_s_setprio(0);                                            \
    half8 pa[2][2];                                                           \
    _Pragma("unroll")                                                         \
    for (int rt = 0; rt < 2; ++rt) {                                          \
        float mt = sc[rt][0][0];                                              \
        _Pragma("unroll")                                                     \
        for (int ct = 0; ct < 4; ++ct)                                        \
            _Pragma("unroll")                                                 \
            for (int r = 0; r < 4; ++r)                                       \
                if (ct || r) mt = fmaxf(mt, sc[rt][ct][r]);                   \
        mt = fmaxf(mt, __shfl_xor(mt, 16));                                   \
        mt = fmaxf(mt, __shfl_xor(mt, 32));                                   \
        const float mn = fmaxf(mrun[rt], mt * CSC);                           \
        const float alpha = exp2f(mrun[rt] - mn);                             \
        mrun[rt] = mn;                                                        \
        float pv_[4][4];                                                      \
        float ls = 0.f;                                                       \
        _Pragma("unroll")                                                     \
        for (int ct = 0; ct < 4; ++ct)                                        \
            _Pragma("unroll")                                                 \
            for (int r = 0; r < 4; ++r) {                                     \
                pv_[ct][r] = exp2f(fmaf(sc[rt][ct][r], CSC, -mn));            \
                ls += pv_[ct][r];                                             \
            }                                                                 \
        ls += __shfl_xor(ls, 16);                                             \
        ls += __shfl_xor(ls, 32);                                             \
        lrun[rt] = lrun[rt] * alpha + ls;                                     \
        _Pragma("unroll")                                                     \
        for (int dct = 0; dct < 4; ++dct)                                     \
            _Pragma("unroll")                                                 \
            for (int r = 0; r < 4; ++r) oacc[rt][dct][r] *= alpha;            \
        /* pack P to f16 pairs and exchange in-register (replaces P-LDS) */   \
        u32 pk_[4][2];                                                        \
        _Pragma("unroll")                                                     \
        for (int ct = 0; ct < 4; ++ct) {                                      \
            pk_[ct][0] = __builtin_bit_cast(u32,                              \
                __builtin_amdgcn_cvt_pkrtz(pv_[ct][0], pv_[ct][1]));          \
            pk_[ct][1] = __builtin_bit_cast(u32,                              \
                __builtin_amdgcn_cvt_pkrtz(pv_[ct][2], pv_[ct][3]));          \
        }                                                                     \
        u32 q02_[4] = {pk_[0][0], pk_[0][1], pk_[2][0], pk_[2][1]};           \
        u32 q13_[4] = {pk_[1][0], pk_[1][1], pk_[3][0], pk_[3][1]};           \
        u32 own_[4], v32_[4], r16_[4], r32_[4], r48_[4], A_[4], B_[4];        \
        _Pragma("unroll")                                                     \
        for (int j = 0; j < 4; ++j) {                                         \
            own_[j] = hi_lg ? q13_[j] : q02_[j];                              \
            v32_[j] = hi_lg ? q02_[j] : q13_[j];                              \
        }                                                                     \
        _Pragma("unroll")                                                     \
        for (int j = 0; j < 4; ++j) {                                         \
            r16_[j] = __shfl_xor((int)own_[j], 16);                           \
            r32_[j] = __shfl_xor((int)v32_[j], 32);                           \
            r48_[j] = __shfl_xor((int)v32_[j], 48);                           \
        }                                                                     \
        _Pragma("unroll")                                                     \
        for (int j = 0; j < 4; ++j) {                                         \
            A_[j] = diag_lg ? (hi_lg ? r32_[j] : r48_[j])                     \
                            : (hi_lg ? r16_[j] : own_[j]);                    \
            B_[j] = diag_lg ? (hi_lg ? r48_[j] : r32_[j])                     \
                            : (hi_lg ? own_[j] : r16_[j]);                    \
        }                                                                     \
        pa[rt][0] = __builtin_bit_cast(half8, (u32x4){A_[0], A_[1], B_[0], B_[1]}); \
        pa[rt][1] = __builtin_bit_cast(half8, (u32x4){A_[2], A_[3], B_[2], B_[3]}); \
    }                                                                         \
    __builtin_amdgcn_s_setprio(1);                                            \
    _Pragma("unroll")                                                         \
    for (int ks2 = 0; ks2 < 2; ++ks2) {                                       \
        _Pragma("unroll")                                                     \
        for (int dct = 0; dct < 4; ++dct) {                                   \
            const int d = dct * 16 + l15;                                     \
            half8 vf = *(half8*)&VtC[d * KVBLK +                              \
                        (((ks2 * 4 + lg) ^ (d & 7) ^ (d >> 3)) * 8)];         \
            _Pragma("unroll")                                                 \
            for (int rt = 0; rt < 2; ++rt)                                    \
                oacc[rt][dct] = __builtin_amdgcn_mfma_f32_16x16x32_f16(       \
                    vf, pa[rt][ks2], oacc[rt][dct], 0, 0, 0);                 \
        }                                                                     \
    }                                                                         \
    __builtin_amdgcn_s_setprio(0);                                            \
    if (PF) { V_STORE(VtN, va_, vb_); }                                       \
    __syncthreads();                                                          \
} while (0)

__global__ __launch_bounds__(256, 4) void attn_mfma_kernel(
    const f16* __restrict__ qkvh, f16* __restrict__ U, float2* __restrict__ ml)
{
    __shared__ f16 Kh0[KVBLK * HD];       // 8 KB
    __shared__ f16 Kh1[KVBLK * HD];       // 8 KB
    __shared__ f16 Vt0[HD * KVBLK];       // 8 KB  [d][k]
    __shared__ f16 Vt1[HD * KVBLK];       // 8 KB  (total 32 KB, no P-LDS)

    const int tid  = threadIdx.x;
    const int lane = tid & 63;
    const int wave = tid >> 6;
    const int l15  = lane & 15;
    const int lg   = lane >> 4;
    const int hi_lg   = (lg >> 1) & 1;
    const int diag_lg = (lg ^ (lg >> 1)) & 1;

    const int nq  = SEQ / QBLK;           // 16
    const int cpx = gridDim.x >> 3;       // 1024/8 = 128
    const int lid = (blockIdx.x & 7) * cpx + (blockIdx.x >> 3);
    const int qc = lid % nq;
    const int hc = lid / nq;
    const int c  = hc & (NCHUNK - 1);
    const int bh = hc / NCHUNK;
    const int h  = bh % NH;
    const int b  = bh / NH;
    const int q0 = qc * QBLK + wave * 32;
    const size_t bS = (size_t)b * SEQ;
    const int t0 = c * CTILES;
    const int tEnd = t0 + CTILES;

    const int krow_l = lane >> 3;         // 0..7
    const int kschk  = (lane & 7) ^ krow_l;
    const f16* kxsrc = qkvh + bS * D3 + DM + h * HD + kschk * 8;

    const int vp  = tid >> 3;             // 0..31
    const int vd0 = (tid & 7) * 8;
    const f16* vsrc0 = qkvh + (bS + 2 * vp) * D3 + 2 * DM + h * HD + vd0;

    half8 qf[2][2];
#pragma unroll
    for (int rt = 0; rt < 2; ++rt)
#pragma unroll
        for (int ks = 0; ks < 2; ++ks)
            qf[rt][ks] = *(const half8*)&qkvh[(bS + q0 + rt * 16 + l15) * D3 +
                                              h * HD + ks * 32 + lg * 8];

    f32x4 oacc[2][4];   // O^T: oacc[rt][dct][r] = O[q=l15(+16rt)][d=dct*16+4lg+r]
#pragma unroll
    for (int rt = 0; rt < 2; ++rt)
#pragma unroll
        for (int dct = 0; dct < 4; ++dct) oacc[rt][dct] = (f32x4){0.f, 0.f, 0.f, 0.f};

    float mrun[2], lrun[2];
#pragma unroll
    for (int rt = 0; rt < 2; ++rt) { mrun[rt] = -INFINITY; lrun[rt] = 0.f; }

    // prologue: stage tile t0 into buf0
    {
        const size_t r0 = (size_t)t0 * KVBLK;
        async_cp16(kxsrc + (r0 + wave * 16 +     krow_l) * D3, &Kh0[(wave * 16) * HD]);
        async_cp16(kxsrc + (r0 + wave * 16 + 8 + krow_l) * D3, &Kh0[(wave * 16 + 8) * HD]);
        half8 va_ = *(const half8*)(vsrc0 + r0 * D3);
        half8 vb_ = *(const half8*)(vsrc0 + r0 * D3 + D3);
        V_STORE(Vt0, va_, vb_);
        __syncthreads();
    }

    for (int t = t0; t < tEnd; t += 2) {
        ATTN_STEP(Kh0, Vt0, Kh1, Vt1, t, true);
        ATTN_STEP(Kh1, Vt1, Kh0, Vt0, t + 1, (t + 2) < tEnd);
    }

    // epilogue: write UNNORMALIZED U (f16) + (m,l) per row
    f16* Uc = U + (size_t)c * MROWS * DM;
#pragma unroll
    for (int rt = 0; rt < 2; ++rt) {
        const int qq = q0 + rt * 16 + l15;
#pragma unroll
        for (int dct = 0; dct < 4; ++dct) {
            half4 o;
#pragma unroll
            for (int r = 0; r < 4; ++r) o[r] = (f16)oacc[rt][dct][r];
            *(half4*)&Uc[(bS + qq) * DM + h * HD + dct * 16 + 4 * lg] = o;
        }
        if (lg == 0)
            ml[(((size_t)c * BS + b) * NH + h) * SEQ + qq] =
                make_float2(mrun[rt], lrun[rt]);
    }
}

// ---------------------------------------------------------------------------
// Split-KV combine: out = (U1*w1 + U2*w2) / (l1*w1 + l2*w2), w_c=exp2(m_c-m).
// ---------------------------------------------------------------------------
__global__ __launch_bounds__(128) void attn_combine_kernel(
    const f16* __restrict__ U, const float2* __restrict__ ml,
    f16* __restrict__ outh)
{
    const int row = blockIdx.x;            // 0..4095 = b*SEQ + q
    const int b = row >> 11;
    const int q = row & (SEQ - 1);
    const int d = threadIdx.x * 8;
    const int h = d >> 6;

    const float2 a1 = ml[(((size_t)0 * BS + b) * NH + h) * SEQ + q];
    const float2 a2 = ml[(((size_t)1 * BS + b) * NH + h) * SEQ + q];
    const float m  = fmaxf(a1.x, a2.x);
    float w1 = exp2f(a1.x - m);
    float w2 = exp2f(a2.x - m);
    const float inv = 1.f / (a1.y * w1 + a2.y * w2);
    w1 *= inv; w2 *= inv;

    half8 u1 = *(const half8*)&U[(size_t)row * DM + d];
    half8 u2 = *(const half8*)&U[(size_t)(MROWS + row) * DM + d];
    half8 o;
#pragma unroll
    for (int e = 0; e < 8; ++e)
        o[e] = (f16)((float)u1[e] * w1 + (float)u2[e] * w2);
    *(half8*)&outh[(size_t)row * DM + d] = o;
}

// ---------------------------------------------------------------------------
extern "C" void kernel_launch(void* const* d_in, const int* in_sizes, int n_in,
                              void* d_out, int out_size, void* d_ws, size_t ws_size,
                              hipStream_t stream) {
    const float* q    = (const float*)d_in[0];
    const float* k    = (const float*)d_in[1];
    const float* v    = (const float*)d_in[2];
    const float* Wqkv = (const float*)d_in[3];
    const float* bqkv = (const float*)d_in[4];
    const float* Wo   = (const float*)d_in[5];
    const float* bo   = (const float*)d_in[6];
    float* out = (float*)d_out;

    char* ws = (char*)d_ws;
    f16* Ain    = (f16*)ws;                        // [4096][3072]
    f16* U      = (f16*)ws;                        // [2][4096][1024] f16 (reuse)
    f16* attn_h = (f16*)ws;                        // [4096][1024] (over U1)
    f16* Wo_h   = (f16*)(ws + 16777216);           // [1024][1024] (reuse)
    float2* ml  = (float2*)(ws + 20971520);        // [2][2][16][2048] (reuse)
    f16* Wqkv_h = (f16*)(ws + 25165824);           // [3072][3072]
    f16* qkv_h  = (f16*)(ws + 44040192);           // [4096][3072]

    conv_concat_kernel<<<dim3(3, MROWS), 256, 0, stream>>>(q, k, v, Ain);
    conv_plain_kernel<<<2048, 256, 0, stream>>>(Wqkv, Wqkv_h, D3 * D3 / 4);

    // QKV projection: 8-phase 256^2, grid 16x12 = 192, 512 threads
    gemm8p_f16_kernel<D3, D3><<<dim3((MROWS / 256) * (D3 / 256)), 512, 0, stream>>>(
        Ain, Wqkv_h, bqkv, qkv_h);

    // attention: split-KV x2, grid 1024, 32 KB LDS
    attn_mfma_kernel<<<dim3(BS * NH * (SEQ / QBLK) * NCHUNK), 256, 0, stream>>>(
        qkv_h, U, ml);

    conv_plain_kernel<<<512, 256, 0, stream>>>(Wo, Wo_h, DM * DM / 4);

    // combine partials -> attn_h (in place over U chunk 0)
    attn_combine_kernel<<<dim3(MROWS), 128, 0, stream>>>(U, ml, attn_h);

    // output projection: 64x128 tile, 2 waves, grid 64x8 = 512
    gemm_out_kernel<<<dim3((MROWS / 64) * (DM / 128)), 128, 0, stream>>>(
        attn_h, Wo_h, bo, out);
}

// Round 16
// 216.089 us; speedup vs baseline: 1.1738x; 1.1738x over previous
//
#include <hip/hip_runtime.h>
#include <cmath>

#define BS   2
#define SEQ  2048
#define DM   1024
#define NH   16
#define HD   64
#define D3   3072
#define MROWS 4096
#define KVBLK 64
#define QBLK  128
#define NTILES (SEQ / KVBLK)   // 32
#define NCHUNK 2               // split-KV factor
#define CTILES (NTILES / NCHUNK)

// log2(e)/8: folds softmax scale and exp->exp2 conversion into one FMA
#define CSC 0.18033688011112042f

typedef _Float16 f16;
typedef __attribute__((ext_vector_type(4))) _Float16 half4;
typedef __attribute__((ext_vector_type(8))) _Float16 half8;
typedef __attribute__((ext_vector_type(4))) float f32x4;
typedef unsigned int u32;
typedef __attribute__((ext_vector_type(2))) u32 u32x2;
typedef __attribute__((ext_vector_type(4))) u32 u32x4;

__device__ __forceinline__ void async_cp16(const void* g, void* s) {
    __builtin_amdgcn_global_load_lds(
        (const __attribute__((address_space(1))) u32*)g,
        (__attribute__((address_space(3))) u32*)s, 16, 0, 0);
}

// ---------------------------------------------------------------------------
// Conversion passes
// ---------------------------------------------------------------------------
__global__ __launch_bounds__(256) void conv_concat_kernel(
    const float* __restrict__ q, const float* __restrict__ k,
    const float* __restrict__ v, f16* __restrict__ out)
{
    const int seg = blockIdx.x;            // 0..2
    const int row = blockIdx.y;            // 0..4095
    const int c   = threadIdx.x * 4;
    const float* src = (seg == 0 ? q : (seg == 1 ? k : v)) + (size_t)row * DM + c;
    float4 x = *(const float4*)src;
    half4 h = {(f16)x.x, (f16)x.y, (f16)x.z, (f16)x.w};
    *(half4*)&out[(size_t)row * D3 + seg * DM + c] = h;
}

__global__ __launch_bounds__(256) void conv_plain_kernel(
    const float* __restrict__ src, f16* __restrict__ dst, int n4)
{
    int i = blockIdx.x * 256 + threadIdx.x;
    const int stride = gridDim.x * 256;
    for (; i < n4; i += stride) {
        float4 x = *(const float4*)&src[(size_t)i * 4];
        half4 h = {(f16)x.x, (f16)x.y, (f16)x.z, (f16)x.w};
        *(half4*)&dst[(size_t)i * 4] = h;
    }
}

// ---------------------------------------------------------------------------
// 8-phase 256x256 fp16 MFMA GEMM (r13 exact: proven (r>>1)&3 swizzle)
// ---------------------------------------------------------------------------
#define SWZ4(r) (((r) >> 1) & 3)

template<int KDIM, int NDIM>
__global__ __launch_bounds__(512, 2) void gemm8p_f16_kernel(
    const f16* __restrict__ A, const f16* __restrict__ W,
    const float* __restrict__ bias, f16* __restrict__ Cout)
{
    __shared__ f16 lds[65536];   // 128 KB

    const int tid  = threadIdx.x;
    const int lane = tid & 63;
    const int wave = tid >> 6;        // 0..7
    const int l15  = lane & 15;
    const int lg   = lane >> 4;
    const int wm   = wave >> 2;       // 0..1 (M half)
    const int wn   = wave & 3;        // 0..3 (N quarter)

    const int cpx = gridDim.x >> 3;   // grid % 8 == 0 (192)
    const int lid = (blockIdx.x & 7) * cpx + (blockIdx.x >> 3);
    const int NTC = NDIM / 256;
    const int tM0 = (lid / NTC) * 256;
    const int tN0 = (lid % NTC) * 256;

    const int rr  = wave * 16 + (lane >> 2);     // 0..127
    const int cs  = (lane & 3) ^ SWZ4(rr);       // pre-swizzled source chunk
    const f16* gA = A + (size_t)(tM0 + rr) * KDIM + cs * 8;
    const f16* gW = W + (size_t)(tN0 + rr) * KDIM + cs * 8;
    const int sbase = wave * 512;                // wave-uniform LDS stage base

    f32x4 acc[8][4];
#pragma unroll
    for (int i = 0; i < 8; ++i)
#pragma unroll
        for (int j = 0; j < 4; ++j) acc[i][j] = (f32x4){0.f, 0.f, 0.f, 0.f};

    const int fch = lg ^ SWZ4(l15);
    const int aro = (wm * 128 + l15) * 32 + fch * 8;            // + mi*512
    const int bro = 32768 + (wn * 64 + l15) * 32 + fch * 8;     // + ni*512

    constexpr int NT = KDIM / 64;    // 48 K-tiles

#define STAGE_A(S, KS, KT) do {                                               \
    const f16* s_ = gA + (size_t)(KT) * 64 + (KS) * 32;                       \
    f16* d_ = &lds[(S) * 16384 + (KS) * 8192 + sbase];                        \
    async_cp16(s_, d_);                                                       \
    async_cp16(s_ + (size_t)128 * KDIM, d_ + 4096);                           \
} while (0)

#define STAGE_B(S, KS, KT) do {                                               \
    const f16* s_ = gW + (size_t)(KT) * 64 + (KS) * 32;                       \
    f16* d_ = &lds[32768 + (S) * 16384 + (KS) * 8192 + sbase];                \
    async_cp16(s_, d_);                                                       \
    async_cp16(s_ + (size_t)128 * KDIM, d_ + 4096);                           \
} while (0)

#define PHASE(S, KS, MH, VMEND, STAGE_STMT) do {                              \
    const int pb_ = (S) * 16384 + (KS) * 8192;                                \
    half8 af[4];                                                              \
    _Pragma("unroll")                                                         \
    for (int mi = 0; mi < 4; ++mi)                                            \
        af[mi] = *(half8*)&lds[pb_ + aro + ((MH) * 4 + mi) * 512];            \
    if ((MH) == 0) {                                                          \
        _Pragma("unroll")                                                     \
        for (int ni = 0; ni < 4; ++ni)                                        \
            wf[ni] = *(half8*)&lds[pb_ + bro + ni * 512];                     \
    }                                                                         \
    STAGE_STMT;                                                               \
    __builtin_amdgcn_s_barrier();                                             \
    asm volatile("s_waitcnt lgkmcnt(0)" ::: "memory");                        \
    __builtin_amdgcn_sched_barrier(0);                                        \
    __builtin_amdgcn_s_setprio(1);                                            \
    _Pragma("unroll")                                                         \
    for (int mi = 0; mi < 4; ++mi)                                            \
        _Pragma("unroll")                                                     \
        for (int ni = 0; ni < 4; ++ni)                                        \
            acc[(MH) * 4 + mi][ni] = __builtin_amdgcn_mfma_f32_16x16x32_f16(  \
                af[mi], wf[ni], acc[(MH) * 4 + mi][ni], 0, 0, 0);             \
    __builtin_amdgcn_s_setprio(0);                                            \
    __builtin_amdgcn_sched_barrier(0);                                        \
    if (VMEND) {                                                              \
        asm volatile("s_waitcnt vmcnt(8)" ::: "memory");                      \
        __builtin_amdgcn_sched_barrier(0);                                    \
    }                                                                         \
    __builtin_amdgcn_s_barrier();                                             \
} while (0)

    // prologue: issue order defines the vmcnt FIFO (12 loads)
    STAGE_A(0, 0, 0); STAGE_B(0, 0, 0);
    STAGE_A(0, 1, 0); STAGE_B(0, 1, 0);
    STAGE_A(1, 0, 1); STAGE_B(1, 0, 1);
    asm volatile("s_waitcnt vmcnt(8)" ::: "memory");
    __builtin_amdgcn_s_barrier();

    half8 wf[4];
    for (int it = 0; it < NT / 2; ++it) {
        const int t   = 2 * it;
        const int t1c = t + 1;
        const int t2c = (t + 2 < NT) ? t + 2 : NT - 1;
        const int t3c = (t + 3 < NT) ? t + 3 : NT - 1;
        PHASE(0, 0, 0, false, STAGE_A(1, 1, t1c));
        PHASE(0, 0, 1, true,  STAGE_B(1, 1, t1c));
        PHASE(0, 1, 0, false, STAGE_A(0, 0, t2c));
        PHASE(0, 1, 1, true,  STAGE_B(0, 0, t2c));
        PHASE(1, 0, 0, false, STAGE_A(0, 1, t2c));
        PHASE(1, 0, 1, true,  STAGE_B(0, 1, t2c));
        PHASE(1, 1, 0, false, STAGE_A(1, 0, t3c));
        PHASE(1, 1, 1, true,  STAGE_B(1, 0, t3c));
    }

#undef PHASE
#undef STAGE_A
#undef STAGE_B

    float bv[4];
#pragma unroll
    for (int ni = 0; ni < 4; ++ni) bv[ni] = bias[tN0 + wn * 64 + ni * 16 + l15];

#pragma unroll
    for (int mi = 0; mi < 8; ++mi)
#pragma unroll
        for (int ni = 0; ni < 4; ++ni)
#pragma unroll
            for (int r = 0; r < 4; ++r) {
                const int m   = tM0 + wm * 128 + mi * 16 + lg * 4 + r;
                const int col = tN0 + wn * 64 + ni * 16 + l15;
                Cout[(size_t)m * NDIM + col] = (f16)(acc[mi][ni][r] + bv[ni]);
            }
}

// ---------------------------------------------------------------------------
// Output-projection GEMM (round-10: 64x128 tile, 2 waves, grid 512)
// ---------------------------------------------------------------------------
__global__ __launch_bounds__(128) void gemm_out_kernel(
    const f16* __restrict__ A, const f16* __restrict__ W,
    const float* __restrict__ bias, float* __restrict__ Cout)
{
    constexpr int KDIM = DM, NDIM = DM;
    __shared__ f16 As[64 * 32];     // 4 KB
    __shared__ f16 Ws[128 * 32];    // 8 KB

    const int tid  = threadIdx.x;   // 0..127
    const int lane = tid & 63;
    const int wave = tid >> 6;      // 0..1
    const int l15  = lane & 15;
    const int lg   = lane >> 4;

    const int cpx = gridDim.x >> 3;             // 512/8 = 64
    const int lid = (blockIdx.x & 7) * cpx + (blockIdx.x >> 3);
    const int NT2 = NDIM / 128;                 // 8
    const int tM0 = (lid / NT2) * 64;
    const int tN0 = (lid % NT2) * 128;

    const int srow = lane >> 2;                 // 0..15
    const int sch  = lane & 3;
    const int ssc  = sch ^ ((srow >> 1) & 3);

    const f16* gA0 = A + (size_t)(tM0 + wave * 32      + srow) * KDIM + ssc * 8;
    const f16* gA1 = A + (size_t)(tM0 + wave * 32 + 16 + srow) * KDIM + ssc * 8;
    const f16* gW0 = W + (size_t)(tN0 + wave * 64      + srow) * KDIM + ssc * 8;
    const f16* gW1 = W + (size_t)(tN0 + wave * 64 + 16 + srow) * KDIM + ssc * 8;
    const f16* gW2 = W + (size_t)(tN0 + wave * 64 + 32 + srow) * KDIM + ssc * 8;
    const f16* gW3 = W + (size_t)(tN0 + wave * 64 + 48 + srow) * KDIM + ssc * 8;
    f16* lA0 = &As[(wave * 32)      * 32];
    f16* lA1 = &As[(wave * 32 + 16) * 32];
    f16* lW0 = &Ws[(wave * 64)      * 32];
    f16* lW1 = &Ws[(wave * 64 + 16) * 32];
    f16* lW2 = &Ws[(wave * 64 + 32) * 32];
    f16* lW3 = &Ws[(wave * 64 + 48) * 32];

    f32x4 acc[4][4];
#pragma unroll
    for (int i = 0; i < 4; ++i)
#pragma unroll
        for (int j = 0; j < 4; ++j) acc[i][j] = (f32x4){0.f, 0.f, 0.f, 0.f};

    const int fsw = (lg ^ ((l15 >> 1) & 3)) * 8;
    int aoff[4], woff[4];
#pragma unroll
    for (int mi = 0; mi < 4; ++mi) aoff[mi] = (mi * 16 + l15) * 32 + fsw;
#pragma unroll
    for (int ni = 0; ni < 4; ++ni) woff[ni] = (wave * 64 + ni * 16 + l15) * 32 + fsw;

    for (int k0 = 0; k0 < KDIM; k0 += 32) {
        __syncthreads();
        async_cp16(gA0 + k0, lA0);
        async_cp16(gA1 + k0, lA1);
        async_cp16(gW0 + k0, lW0);
        async_cp16(gW1 + k0, lW1);
        async_cp16(gW2 + k0, lW2);
        async_cp16(gW3 + k0, lW3);
        __syncthreads();

        half8 af[4], wf[4];
#pragma unroll
        for (int mi = 0; mi < 4; ++mi) af[mi] = *(half8*)&As[aoff[mi]];
#pragma unroll
        for (int ni = 0; ni < 4; ++ni) wf[ni] = *(half8*)&Ws[woff[ni]];
#pragma unroll
        for (int mi = 0; mi < 4; ++mi)
#pragma unroll
            for (int ni = 0; ni < 4; ++ni)
                acc[mi][ni] = __builtin_amdgcn_mfma_f32_16x16x32_f16(
                    af[mi], wf[ni], acc[mi][ni], 0, 0, 0);
    }

    float bv[4];
#pragma unroll
    for (int ni = 0; ni < 4; ++ni) bv[ni] = bias[tN0 + wave * 64 + ni * 16 + l15];

#pragma unroll
    for (int mi = 0; mi < 4; ++mi)
#pragma unroll
        for (int ni = 0; ni < 4; ++ni)
#pragma unroll
            for (int r = 0; r < 4; ++r) {
                const int m   = tM0 + mi * 16 + lg * 4 + r;
                const int col = tN0 + wave * 64 + ni * 16 + l15;
                Cout[(size_t)m * NDIM + col] = acc[mi][ni][r] + bv[ni];
            }
}

// ---------------------------------------------------------------------------
// fp16 MFMA flash attention, swapped-operand, split-KV x2, NO P-LDS
// (in-register P exchange via 3x shfl_xor). LDS 32 KB -> 4 blocks/CU.
// ROUND-16 CHANGE vs r15: __launch_bounds__(256) (no min-waves cap) —
// r15's (256,4) capped VGPR at 128 -> spill -> 193 MB scratch traffic.
// ---------------------------------------------------------------------------

#define V_STORE(VtN, va, vb) do {                                             \
    u32x4 aw_ = __builtin_bit_cast(u32x4, va);                                \
    u32x4 bw_ = __builtin_bit_cast(u32x4, vb);                                \
    _Pragma("unroll")                                                         \
    for (int wd_ = 0; wd_ < 4; ++wd_) {                                       \
        u32 lo_ = __builtin_amdgcn_perm(bw_[wd_], aw_[wd_], 0x05040100u);     \
        u32 hi_ = __builtin_amdgcn_perm(bw_[wd_], aw_[wd_], 0x07060302u);     \
        const int dl_ = vd0 + 2 * wd_;                                        \
        const int dh_ = dl_ + 1;                                              \
        *(u32*)&VtN[dl_ * KVBLK + (((vp >> 2) ^ (dl_ & 7) ^ (dl_ >> 3)) * 8)  \
                    + 2 * (vp & 3)] = lo_;                                    \
        *(u32*)&VtN[dh_ * KVBLK + (((vp >> 2) ^ (dh_ & 7) ^ (dh_ >> 3)) * 8)  \
                    + 2 * (vp & 3)] = hi_;                                    \
    }                                                                         \
} while (0)

#define ATTN_STEP(KhC, VtC, KhN, VtN, TT, PF) do {                            \
    half8 va_ = {}, vb_ = {};                                                 \
    if (PF) {                                                                 \
        const size_t nro_ = (size_t)((TT) + 1) * KVBLK;                       \
        async_cp16(kxsrc + (nro_ + wave * 16 +     krow_l) * D3,              \
                   &KhN[(wave * 16) * HD]);                                   \
        async_cp16(kxsrc + (nro_ + wave * 16 + 8 + krow_l) * D3,              \
                   &KhN[(wave * 16 + 8) * HD]);                               \
        va_ = *(const half8*)(vsrc0 + nro_ * D3);                             \
        vb_ = *(const half8*)(vsrc0 + nro_ * D3 + D3);                        \
    }                                                                         \
    f32x4 sc[2][4];                                                           \
    _Pragma("unroll")                                                         \
    for (int rt = 0; rt < 2; ++rt)                                            \
        _Pragma("unroll")                                                     \
        for (int ct = 0; ct < 4; ++ct) sc[rt][ct] = (f32x4){0.f,0.f,0.f,0.f}; \
    __builtin_amdgcn_s_setprio(1);                                            \
    _Pragma("unroll")                                                         \
    for (int ct = 0; ct < 4; ++ct) {                                          \
        const int krow = ct * 16 + l15;                                       \
        _Pragma("unroll")                                                     \
        for (int ks = 0; ks < 2; ++ks) {                                      \
            half8 kf = *(half8*)&KhC[krow * HD +                              \
                                     (((ks * 4 + lg) ^ (krow & 7)) * 8)];     \
            _Pragma("unroll")                                                 \
            for (int rt = 0; rt < 2; ++rt)                                    \
                sc[rt][ct] = __builtin_amdgcn_mfma_f32_16x16x32_f16(          \
                    kf, qf[rt][ks], sc[rt][ct], 0, 0, 0);                     \
        }                                                                     \
    }                                                                         \
    __builtin_amdgcn_s_setprio(0);                                            \
    half8 pa[2][2];                                                           \
    _Pragma("unroll")                                                         \
    for (int rt = 0; rt < 2; ++rt) {                                          \
        float mt = sc[rt][0][0];                                              \
        _Pragma("unroll")                                                     \
        for (int ct = 0; ct < 4; ++ct)                                        \
            _Pragma("unroll")                                                 \
            for (int r = 0; r < 4; ++r)                                       \
                if (ct || r) mt = fmaxf(mt, sc[rt][ct][r]);                   \
        mt = fmaxf(mt, __shfl_xor(mt, 16));                                   \
        mt = fmaxf(mt, __shfl_xor(mt, 32));                                   \
        const float mn = fmaxf(mrun[rt], mt * CSC);                           \
        const float alpha = exp2f(mrun[rt] - mn);                             \
        mrun[rt] = mn;                                                        \
        float pv_[4][4];                                                      \
        float ls = 0.f;                                                       \
        _Pragma("unroll")                                                     \
        for (int ct = 0; ct < 4; ++ct)                                        \
            _Pragma("unroll")                                                 \
            for (int r = 0; r < 4; ++r) {                                     \
                pv_[ct][r] = exp2f(fmaf(sc[rt][ct][r], CSC, -mn));            \
                ls += pv_[ct][r];                                             \
            }                                                                 \
        ls += __shfl_xor(ls, 16);                                             \
        ls += __shfl_xor(ls, 32);                                             \
        lrun[rt] = lrun[rt] * alpha + ls;                                     \
        _Pragma("unroll")                                                     \
        for (int dct = 0; dct < 4; ++dct)                                     \
            _Pragma("unroll")                                                 \
            for (int r = 0; r < 4; ++r) oacc[rt][dct][r] *= alpha;            \
        /* pack P to f16 pairs and exchange in-register (replaces P-LDS) */   \
        u32 pk_[4][2];                                                        \
        _Pragma("unroll")                                                     \
        for (int ct = 0; ct < 4; ++ct) {                                      \
            pk_[ct][0] = __builtin_bit_cast(u32,                              \
                __builtin_amdgcn_cvt_pkrtz(pv_[ct][0], pv_[ct][1]));          \
            pk_[ct][1] = __builtin_bit_cast(u32,                              \
                __builtin_amdgcn_cvt_pkrtz(pv_[ct][2], pv_[ct][3]));          \
        }                                                                     \
        u32 q02_[4] = {pk_[0][0], pk_[0][1], pk_[2][0], pk_[2][1]};           \
        u32 q13_[4] = {pk_[1][0], pk_[1][1], pk_[3][0], pk_[3][1]};           \
        u32 own_[4], v32_[4], r16_[4], r32_[4], r48_[4], A_[4], B_[4];        \
        _Pragma("unroll")                                                     \
        for (int j = 0; j < 4; ++j) {                                         \
            own_[j] = hi_lg ? q13_[j] : q02_[j];                              \
            v32_[j] = hi_lg ? q02_[j] : q13_[j];                              \
        }                                                                     \
        _Pragma("unroll")                                                     \
        for (int j = 0; j < 4; ++j) {                                         \
            r16_[j] = __shfl_xor((int)own_[j], 16);                           \
            r32_[j] = __shfl_xor((int)v32_[j], 32);                           \
            r48_[j] = __shfl_xor((int)v32_[j], 48);                           \
        }                                                                     \
        _Pragma("unroll")                                                     \
        for (int j = 0; j < 4; ++j) {                                         \
            A_[j] = diag_lg ? (hi_lg ? r32_[j] : r48_[j])                     \
                            : (hi_lg ? r16_[j] : own_[j]);                    \
            B_[j] = diag_lg ? (hi_lg ? r48_[j] : r32_[j])                     \
                            : (hi_lg ? own_[j] : r16_[j]);                    \
        }                                                                     \
        pa[rt][0] = __builtin_bit_cast(half8, (u32x4){A_[0], A_[1], B_[0], B_[1]}); \
        pa[rt][1] = __builtin_bit_cast(half8, (u32x4){A_[2], A_[3], B_[2], B_[3]}); \
    }                                                                         \
    __builtin_amdgcn_s_setprio(1);                                            \
    _Pragma("unroll")                                                         \
    for (int ks2 = 0; ks2 < 2; ++ks2) {                                       \
        _Pragma("unroll")                                                     \
        for (int dct = 0; dct < 4; ++dct) {                                   \
            const int d = dct * 16 + l15;                                     \
            half8 vf = *(half8*)&VtC[d * KVBLK +                              \
                        (((ks2 * 4 + lg) ^ (d & 7) ^ (d >> 3)) * 8)];         \
            _Pragma("unroll")                                                 \
            for (int rt = 0; rt < 2; ++rt)                                    \
                oacc[rt][dct] = __builtin_amdgcn_mfma_f32_16x16x32_f16(       \
                    vf, pa[rt][ks2], oacc[rt][dct], 0, 0, 0);                 \
        }                                                                     \
    }                                                                         \
    __builtin_amdgcn_s_setprio(0);                                            \
    if (PF) { V_STORE(VtN, va_, vb_); }                                       \
    __syncthreads();                                                          \
} while (0)

__global__ __launch_bounds__(256) void attn_mfma_kernel(
    const f16* __restrict__ qkvh, f16* __restrict__ U, float2* __restrict__ ml)
{
    __shared__ f16 Kh0[KVBLK * HD];       // 8 KB
    __shared__ f16 Kh1[KVBLK * HD];       // 8 KB
    __shared__ f16 Vt0[HD * KVBLK];       // 8 KB  [d][k]
    __shared__ f16 Vt1[HD * KVBLK];       // 8 KB  (total 32 KB, no P-LDS)

    const int tid  = threadIdx.x;
    const int lane = tid & 63;
    const int wave = tid >> 6;
    const int l15  = lane & 15;
    const int lg   = lane >> 4;
    const int hi_lg   = (lg >> 1) & 1;
    const int diag_lg = (lg ^ (lg >> 1)) & 1;

    const int nq  = SEQ / QBLK;           // 16
    const int cpx = gridDim.x >> 3;       // 1024/8 = 128
    const int lid = (blockIdx.x & 7) * cpx + (blockIdx.x >> 3);
    const int qc = lid % nq;
    const int hc = lid / nq;
    const int c  = hc & (NCHUNK - 1);
    const int bh = hc / NCHUNK;
    const int h  = bh % NH;
    const int b  = bh / NH;
    const int q0 = qc * QBLK + wave * 32;
    const size_t bS = (size_t)b * SEQ;
    const int t0 = c * CTILES;
    const int tEnd = t0 + CTILES;

    const int krow_l = lane >> 3;         // 0..7
    const int kschk  = (lane & 7) ^ krow_l;
    const f16* kxsrc = qkvh + bS * D3 + DM + h * HD + kschk * 8;

    const int vp  = tid >> 3;             // 0..31
    const int vd0 = (tid & 7) * 8;
    const f16* vsrc0 = qkvh + (bS + 2 * vp) * D3 + 2 * DM + h * HD + vd0;

    half8 qf[2][2];
#pragma unroll
    for (int rt = 0; rt < 2; ++rt)
#pragma unroll
        for (int ks = 0; ks < 2; ++ks)
            qf[rt][ks] = *(const half8*)&qkvh[(bS + q0 + rt * 16 + l15) * D3 +
                                              h * HD + ks * 32 + lg * 8];

    f32x4 oacc[2][4];   // O^T: oacc[rt][dct][r] = O[q=l15(+16rt)][d=dct*16+4lg+r]
#pragma unroll
    for (int rt = 0; rt < 2; ++rt)
#pragma unroll
        for (int dct = 0; dct < 4; ++dct) oacc[rt][dct] = (f32x4){0.f, 0.f, 0.f, 0.f};

    float mrun[2], lrun[2];
#pragma unroll
    for (int rt = 0; rt < 2; ++rt) { mrun[rt] = -INFINITY; lrun[rt] = 0.f; }

    // prologue: stage tile t0 into buf0
    {
        const size_t r0 = (size_t)t0 * KVBLK;
        async_cp16(kxsrc + (r0 + wave * 16 +     krow_l) * D3, &Kh0[(wave * 16) * HD]);
        async_cp16(kxsrc + (r0 + wave * 16 + 8 + krow_l) * D3, &Kh0[(wave * 16 + 8) * HD]);
        half8 va_ = *(const half8*)(vsrc0 + r0 * D3);
        half8 vb_ = *(const half8*)(vsrc0 + r0 * D3 + D3);
        V_STORE(Vt0, va_, vb_);
        __syncthreads();
    }

    for (int t = t0; t < tEnd; t += 2) {
        ATTN_STEP(Kh0, Vt0, Kh1, Vt1, t, true);
        ATTN_STEP(Kh1, Vt1, Kh0, Vt0, t + 1, (t + 2) < tEnd);
    }

    // epilogue: write UNNORMALIZED U (f16) + (m,l) per row
    f16* Uc = U + (size_t)c * MROWS * DM;
#pragma unroll
    for (int rt = 0; rt < 2; ++rt) {
        const int qq = q0 + rt * 16 + l15;
#pragma unroll
        for (int dct = 0; dct < 4; ++dct) {
            half4 o;
#pragma unroll
            for (int r = 0; r < 4; ++r) o[r] = (f16)oacc[rt][dct][r];
            *(half4*)&Uc[(bS + qq) * DM + h * HD + dct * 16 + 4 * lg] = o;
        }
        if (lg == 0)
            ml[(((size_t)c * BS + b) * NH + h) * SEQ + qq] =
                make_float2(mrun[rt], lrun[rt]);
    }
}

// ---------------------------------------------------------------------------
// Split-KV combine: out = (U1*w1 + U2*w2) / (l1*w1 + l2*w2), w_c=exp2(m_c-m).
// ---------------------------------------------------------------------------
__global__ __launch_bounds__(128) void attn_combine_kernel(
    const f16* __restrict__ U, const float2* __restrict__ ml,
    f16* __restrict__ outh)
{
    const int row = blockIdx.x;            // 0..4095 = b*SEQ + q
    const int b = row >> 11;
    const int q = row & (SEQ - 1);
    const int d = threadIdx.x * 8;
    const int h = d >> 6;

    const float2 a1 = ml[(((size_t)0 * BS + b) * NH + h) * SEQ + q];
    const float2 a2 = ml[(((size_t)1 * BS + b) * NH + h) * SEQ + q];
    const float m  = fmaxf(a1.x, a2.x);
    float w1 = exp2f(a1.x - m);
    float w2 = exp2f(a2.x - m);
    const float inv = 1.f / (a1.y * w1 + a2.y * w2);
    w1 *= inv; w2 *= inv;

    half8 u1 = *(const half8*)&U[(size_t)row * DM + d];
    half8 u2 = *(const half8*)&U[(size_t)(MROWS + row) * DM + d];
    half8 o;
#pragma unroll
    for (int e = 0; e < 8; ++e)
        o[e] = (f16)((float)u1[e] * w1 + (float)u2[e] * w2);
    *(half8*)&outh[(size_t)row * DM + d] = o;
}

// ---------------------------------------------------------------------------
extern "C" void kernel_launch(void* const* d_in, const int* in_sizes, int n_in,
                              void* d_out, int out_size, void* d_ws, size_t ws_size,
                              hipStream_t stream) {
    const float* q    = (const float*)d_in[0];
    const float* k    = (const float*)d_in[1];
    const float* v    = (const float*)d_in[2];
    const float* Wqkv = (const float*)d_in[3];
    const float* bqkv = (const float*)d_in[4];
    const float* Wo   = (const float*)d_in[5];
    const float* bo   = (const float*)d_in[6];
    float* out = (float*)d_out;

    char* ws = (char*)d_ws;
    f16* Ain    = (f16*)ws;                        // [4096][3072]
    f16* U      = (f16*)ws;                        // [2][4096][1024] f16 (reuse)
    f16* attn_h = (f16*)ws;                        // [4096][1024] (over U1)
    f16* Wo_h   = (f16*)(ws + 16777216);           // [1024][1024] (reuse)
    float2* ml  = (float2*)(ws + 20971520);        // [2][2][16][2048] (reuse)
    f16* Wqkv_h = (f16*)(ws + 25165824);           // [3072][3072]
    f16* qkv_h  = (f16*)(ws + 44040192);           // [4096][3072]

    conv_concat_kernel<<<dim3(3, MROWS), 256, 0, stream>>>(q, k, v, Ain);
    conv_plain_kernel<<<2048, 256, 0, stream>>>(Wqkv, Wqkv_h, D3 * D3 / 4);

    // QKV projection: 8-phase 256^2, grid 16x12 = 192, 512 threads
    gemm8p_f16_kernel<D3, D3><<<dim3((MROWS / 256) * (D3 / 256)), 512, 0, stream>>>(
        Ain, Wqkv_h, bqkv, qkv_h);

    // attention: split-KV x2, grid 1024, 32 KB LDS, no VGPR cap
    attn_mfma_kernel<<<dim3(BS * NH * (SEQ / QBLK) * NCHUNK), 256, 0, stream>>>(
        qkv_h, U, ml);

    conv_plain_kernel<<<512, 256, 0, stream>>>(Wo, Wo_h, DM * DM / 4);

    // combine partials -> attn_h (in place over U chunk 0)
    attn_combine_kernel<<<dim3(MROWS), 128, 0, stream>>>(U, ml, attn_h);

    // output projection: 64x128 tile, 2 waves, grid 64x8 = 512
    gemm_out_kernel<<<dim3((MROWS / 64) * (DM / 128)), 128, 0, stream>>>(
        attn_h, Wo_h, bo, out);
}

// Round 17
// 194.758 us; speedup vs baseline: 1.3023x; 1.1095x over previous
//
#include <hip/hip_runtime.h>
#include <cmath>

#define BS   2
#define SEQ  2048
#define DM   1024
#define NH   16
#define HD   64
#define D3   3072
#define MROWS 4096
#define KVBLK 64
#define QBLK  128
#define NTILES (SEQ / KVBLK)   // 32

// log2(e)/8: folds softmax scale and exp->exp2 conversion into one FMA
#define CSC 0.18033688011112042f

typedef _Float16 f16;
typedef __attribute__((ext_vector_type(4))) _Float16 half4;
typedef __attribute__((ext_vector_type(8))) _Float16 half8;
typedef __attribute__((ext_vector_type(4))) float f32x4;
typedef unsigned int u32;
typedef __attribute__((ext_vector_type(2))) u32 u32x2;
typedef __attribute__((ext_vector_type(4))) u32 u32x4;

__device__ __forceinline__ void async_cp16(const void* g, void* s) {
    __builtin_amdgcn_global_load_lds(
        (const __attribute__((address_space(1))) u32*)g,
        (__attribute__((address_space(3))) u32*)s, 16, 0, 0);
}

// ---------------------------------------------------------------------------
// Conversion passes
// ---------------------------------------------------------------------------
__global__ __launch_bounds__(256) void conv_concat_kernel(
    const float* __restrict__ q, const float* __restrict__ k,
    const float* __restrict__ v, f16* __restrict__ out)
{
    const int seg = blockIdx.x;            // 0..2
    const int row = blockIdx.y;            // 0..4095
    const int c   = threadIdx.x * 4;
    const float* src = (seg == 0 ? q : (seg == 1 ? k : v)) + (size_t)row * DM + c;
    float4 x = *(const float4*)src;
    half4 h = {(f16)x.x, (f16)x.y, (f16)x.z, (f16)x.w};
    *(half4*)&out[(size_t)row * D3 + seg * DM + c] = h;
}

__global__ __launch_bounds__(256) void conv_plain_kernel(
    const float* __restrict__ src, f16* __restrict__ dst, int n4)
{
    int i = blockIdx.x * 256 + threadIdx.x;
    const int stride = gridDim.x * 256;
    for (; i < n4; i += stride) {
        float4 x = *(const float4*)&src[(size_t)i * 4];
        half4 h = {(f16)x.x, (f16)x.y, (f16)x.z, (f16)x.w};
        *(half4*)&dst[(size_t)i * 4] = h;
    }
}

// ---------------------------------------------------------------------------
// 8-phase 256x256 fp16 MFMA GEMM (r13 exact: proven (r>>1)&3 swizzle)
// ---------------------------------------------------------------------------
#define SWZ4(r) (((r) >> 1) & 3)

template<int KDIM, int NDIM>
__global__ __launch_bounds__(512, 2) void gemm8p_f16_kernel(
    const f16* __restrict__ A, const f16* __restrict__ W,
    const float* __restrict__ bias, f16* __restrict__ Cout)
{
    __shared__ f16 lds[65536];   // 128 KB

    const int tid  = threadIdx.x;
    const int lane = tid & 63;
    const int wave = tid >> 6;        // 0..7
    const int l15  = lane & 15;
    const int lg   = lane >> 4;
    const int wm   = wave >> 2;       // 0..1 (M half)
    const int wn   = wave & 3;        // 0..3 (N quarter)

    const int cpx = gridDim.x >> 3;   // grid % 8 == 0 (192)
    const int lid = (blockIdx.x & 7) * cpx + (blockIdx.x >> 3);
    const int NTC = NDIM / 256;
    const int tM0 = (lid / NTC) * 256;
    const int tN0 = (lid % NTC) * 256;

    const int rr  = wave * 16 + (lane >> 2);     // 0..127
    const int cs  = (lane & 3) ^ SWZ4(rr);       // pre-swizzled source chunk
    const f16* gA = A + (size_t)(tM0 + rr) * KDIM + cs * 8;
    const f16* gW = W + (size_t)(tN0 + rr) * KDIM + cs * 8;
    const int sbase = wave * 512;                // wave-uniform LDS stage base

    f32x4 acc[8][4];
#pragma unroll
    for (int i = 0; i < 8; ++i)
#pragma unroll
        for (int j = 0; j < 4; ++j) acc[i][j] = (f32x4){0.f, 0.f, 0.f, 0.f};

    const int fch = lg ^ SWZ4(l15);
    const int aro = (wm * 128 + l15) * 32 + fch * 8;            // + mi*512
    const int bro = 32768 + (wn * 64 + l15) * 32 + fch * 8;     // + ni*512

    constexpr int NT = KDIM / 64;    // 48 K-tiles

#define STAGE_A(S, KS, KT) do {                                               \
    const f16* s_ = gA + (size_t)(KT) * 64 + (KS) * 32;                       \
    f16* d_ = &lds[(S) * 16384 + (KS) * 8192 + sbase];                        \
    async_cp16(s_, d_);                                                       \
    async_cp16(s_ + (size_t)128 * KDIM, d_ + 4096);                           \
} while (0)

#define STAGE_B(S, KS, KT) do {                                               \
    const f16* s_ = gW + (size_t)(KT) * 64 + (KS) * 32;                       \
    f16* d_ = &lds[32768 + (S) * 16384 + (KS) * 8192 + sbase];                \
    async_cp16(s_, d_);                                                       \
    async_cp16(s_ + (size_t)128 * KDIM, d_ + 4096);                           \
} while (0)

#define PHASE(S, KS, MH, VMEND, STAGE_STMT) do {                              \
    const int pb_ = (S) * 16384 + (KS) * 8192;                                \
    half8 af[4];                                                              \
    _Pragma("unroll")                                                         \
    for (int mi = 0; mi < 4; ++mi)                                            \
        af[mi] = *(half8*)&lds[pb_ + aro + ((MH) * 4 + mi) * 512];            \
    if ((MH) == 0) {                                                          \
        _Pragma("unroll")                                                     \
        for (int ni = 0; ni < 4; ++ni)                                        \
            wf[ni] = *(half8*)&lds[pb_ + bro + ni * 512];                     \
    }                                                                         \
    STAGE_STMT;                                                               \
    __builtin_amdgcn_s_barrier();                                             \
    asm volatile("s_waitcnt lgkmcnt(0)" ::: "memory");                        \
    __builtin_amdgcn_sched_barrier(0);                                        \
    __builtin_amdgcn_s_setprio(1);                                            \
    _Pragma("unroll")                                                         \
    for (int mi = 0; mi < 4; ++mi)                                            \
        _Pragma("unroll")                                                     \
        for (int ni = 0; ni < 4; ++ni)                                        \
            acc[(MH) * 4 + mi][ni] = __builtin_amdgcn_mfma_f32_16x16x32_f16(  \
                af[mi], wf[ni], acc[(MH) * 4 + mi][ni], 0, 0, 0);             \
    __builtin_amdgcn_s_setprio(0);                                            \
    __builtin_amdgcn_sched_barrier(0);                                        \
    if (VMEND) {                                                              \
        asm volatile("s_waitcnt vmcnt(8)" ::: "memory");                      \
        __builtin_amdgcn_sched_barrier(0);                                    \
    }                                                                         \
    __builtin_amdgcn_s_barrier();                                             \
} while (0)

    // prologue: issue order defines the vmcnt FIFO (12 loads)
    STAGE_A(0, 0, 0); STAGE_B(0, 0, 0);
    STAGE_A(0, 1, 0); STAGE_B(0, 1, 0);
    STAGE_A(1, 0, 1); STAGE_B(1, 0, 1);
    asm volatile("s_waitcnt vmcnt(8)" ::: "memory");
    __builtin_amdgcn_s_barrier();

    half8 wf[4];
    for (int it = 0; it < NT / 2; ++it) {
        const int t   = 2 * it;
        const int t1c = t + 1;
        const int t2c = (t + 2 < NT) ? t + 2 : NT - 1;
        const int t3c = (t + 3 < NT) ? t + 3 : NT - 1;
        PHASE(0, 0, 0, false, STAGE_A(1, 1, t1c));
        PHASE(0, 0, 1, true,  STAGE_B(1, 1, t1c));
        PHASE(0, 1, 0, false, STAGE_A(0, 0, t2c));
        PHASE(0, 1, 1, true,  STAGE_B(0, 0, t2c));
        PHASE(1, 0, 0, false, STAGE_A(0, 1, t2c));
        PHASE(1, 0, 1, true,  STAGE_B(0, 1, t2c));
        PHASE(1, 1, 0, false, STAGE_A(1, 0, t3c));
        PHASE(1, 1, 1, true,  STAGE_B(1, 0, t3c));
    }

#undef PHASE
#undef STAGE_A
#undef STAGE_B

    float bv[4];
#pragma unroll
    for (int ni = 0; ni < 4; ++ni) bv[ni] = bias[tN0 + wn * 64 + ni * 16 + l15];

#pragma unroll
    for (int mi = 0; mi < 8; ++mi)
#pragma unroll
        for (int ni = 0; ni < 4; ++ni)
#pragma unroll
            for (int r = 0; r < 4; ++r) {
                const int m   = tM0 + wm * 128 + mi * 16 + lg * 4 + r;
                const int col = tN0 + wn * 64 + ni * 16 + l15;
                Cout[(size_t)m * NDIM + col] = (f16)(acc[mi][ni][r] + bv[ni]);
            }
}

// ---------------------------------------------------------------------------
// Output-projection GEMM (round-10: 64x128 tile, 2 waves, grid 512)
// ---------------------------------------------------------------------------
__global__ __launch_bounds__(128) void gemm_out_kernel(
    const f16* __restrict__ A, const f16* __restrict__ W,
    const float* __restrict__ bias, float* __restrict__ Cout)
{
    constexpr int KDIM = DM, NDIM = DM;
    __shared__ f16 As[64 * 32];     // 4 KB
    __shared__ f16 Ws[128 * 32];    // 8 KB

    const int tid  = threadIdx.x;   // 0..127
    const int lane = tid & 63;
    const int wave = tid >> 6;      // 0..1
    const int l15  = lane & 15;
    const int lg   = lane >> 4;

    const int cpx = gridDim.x >> 3;             // 512/8 = 64
    const int lid = (blockIdx.x & 7) * cpx + (blockIdx.x >> 3);
    const int NT2 = NDIM / 128;                 // 8
    const int tM0 = (lid / NT2) * 64;
    const int tN0 = (lid % NT2) * 128;

    const int srow = lane >> 2;                 // 0..15
    const int sch  = lane & 3;
    const int ssc  = sch ^ ((srow >> 1) & 3);

    const f16* gA0 = A + (size_t)(tM0 + wave * 32      + srow) * KDIM + ssc * 8;
    const f16* gA1 = A + (size_t)(tM0 + wave * 32 + 16 + srow) * KDIM + ssc * 8;
    const f16* gW0 = W + (size_t)(tN0 + wave * 64      + srow) * KDIM + ssc * 8;
    const f16* gW1 = W + (size_t)(tN0 + wave * 64 + 16 + srow) * KDIM + ssc * 8;
    const f16* gW2 = W + (size_t)(tN0 + wave * 64 + 32 + srow) * KDIM + ssc * 8;
    const f16* gW3 = W + (size_t)(tN0 + wave * 64 + 48 + srow) * KDIM + ssc * 8;
    f16* lA0 = &As[(wave * 32)      * 32];
    f16* lA1 = &As[(wave * 32 + 16) * 32];
    f16* lW0 = &Ws[(wave * 64)      * 32];
    f16* lW1 = &Ws[(wave * 64 + 16) * 32];
    f16* lW2 = &Ws[(wave * 64 + 32) * 32];
    f16* lW3 = &Ws[(wave * 64 + 48) * 32];

    f32x4 acc[4][4];
#pragma unroll
    for (int i = 0; i < 4; ++i)
#pragma unroll
        for (int j = 0; j < 4; ++j) acc[i][j] = (f32x4){0.f, 0.f, 0.f, 0.f};

    const int fsw = (lg ^ ((l15 >> 1) & 3)) * 8;
    int aoff[4], woff[4];
#pragma unroll
    for (int mi = 0; mi < 4; ++mi) aoff[mi] = (mi * 16 + l15) * 32 + fsw;
#pragma unroll
    for (int ni = 0; ni < 4; ++ni) woff[ni] = (wave * 64 + ni * 16 + l15) * 32 + fsw;

    for (int k0 = 0; k0 < KDIM; k0 += 32) {
        __syncthreads();
        async_cp16(gA0 + k0, lA0);
        async_cp16(gA1 + k0, lA1);
        async_cp16(gW0 + k0, lW0);
        async_cp16(gW1 + k0, lW1);
        async_cp16(gW2 + k0, lW2);
        async_cp16(gW3 + k0, lW3);
        __syncthreads();

        half8 af[4], wf[4];
#pragma unroll
        for (int mi = 0; mi < 4; ++mi) af[mi] = *(half8*)&As[aoff[mi]];
#pragma unroll
        for (int ni = 0; ni < 4; ++ni) wf[ni] = *(half8*)&Ws[woff[ni]];
#pragma unroll
        for (int mi = 0; mi < 4; ++mi)
#pragma unroll
            for (int ni = 0; ni < 4; ++ni)
                acc[mi][ni] = __builtin_amdgcn_mfma_f32_16x16x32_f16(
                    af[mi], wf[ni], acc[mi][ni], 0, 0, 0);
    }

    float bv[4];
#pragma unroll
    for (int ni = 0; ni < 4; ++ni) bv[ni] = bias[tN0 + wave * 64 + ni * 16 + l15];

#pragma unroll
    for (int mi = 0; mi < 4; ++mi)
#pragma unroll
        for (int ni = 0; ni < 4; ++ni)
#pragma unroll
            for (int r = 0; r < 4; ++r) {
                const int m   = tM0 + mi * 16 + lg * 4 + r;
                const int col = tN0 + wave * 64 + ni * 16 + l15;
                Cout[(size_t)m * NDIM + col] = acc[mi][ni][r] + bv[ni];
            }
}

// ---------------------------------------------------------------------------
// fp16 MFMA flash attention, swapped-operand form (r13 structure).
// ROUND-17 CHANGES (chain-shortening only, structure identical):
//  1. parallel fmax tree (depth 4 instead of 15-deep serial fold)
//  2. T13 defer-max: skip alpha/rescale when max growth <= 8 (log2 units);
//     P bounded by 2^8 (safe in f16); first tile enters branch (-inf path).
// ---------------------------------------------------------------------------

#define V_STORE(VtN, va, vb) do {                                             \
    u32x4 aw_ = __builtin_bit_cast(u32x4, va);                                \
    u32x4 bw_ = __builtin_bit_cast(u32x4, vb);                                \
    _Pragma("unroll")                                                         \
    for (int wd_ = 0; wd_ < 4; ++wd_) {                                       \
        u32 lo_ = __builtin_amdgcn_perm(bw_[wd_], aw_[wd_], 0x05040100u);     \
        u32 hi_ = __builtin_amdgcn_perm(bw_[wd_], aw_[wd_], 0x07060302u);     \
        const int dl_ = vd0 + 2 * wd_;                                        \
        const int dh_ = dl_ + 1;                                              \
        *(u32*)&VtN[dl_ * KVBLK + (((vp >> 2) ^ (dl_ & 7) ^ (dl_ >> 3)) * 8)  \
                    + 2 * (vp & 3)] = lo_;                                    \
        *(u32*)&VtN[dh_ * KVBLK + (((vp >> 2) ^ (dh_ & 7) ^ (dh_ >> 3)) * 8)  \
                    + 2 * (vp & 3)] = hi_;                                    \
    }                                                                         \
} while (0)

#define ATTN_STEP(KhC, VtC, KhN, VtN, TT, PF) do {                            \
    half8 va_ = {}, vb_ = {};                                                 \
    if (PF) {                                                                 \
        const size_t nro_ = (size_t)((TT) + 1) * KVBLK;                       \
        async_cp16(kxsrc + (nro_ + wave * 16 +     krow_l) * D3,              \
                   &KhN[(wave * 16) * HD]);                                   \
        async_cp16(kxsrc + (nro_ + wave * 16 + 8 + krow_l) * D3,              \
                   &KhN[(wave * 16 + 8) * HD]);                               \
        va_ = *(const half8*)(vsrc0 + nro_ * D3);                             \
        vb_ = *(const half8*)(vsrc0 + nro_ * D3 + D3);                        \
    }                                                                         \
    f32x4 sc[2][4];                                                           \
    _Pragma("unroll")                                                         \
    for (int rt = 0; rt < 2; ++rt)                                            \
        _Pragma("unroll")                                                     \
        for (int ct = 0; ct < 4; ++ct) sc[rt][ct] = (f32x4){0.f,0.f,0.f,0.f}; \
    __builtin_amdgcn_s_setprio(1);                                            \
    _Pragma("unroll")                                                         \
    for (int ct = 0; ct < 4; ++ct) {                                          \
        const int krow = ct * 16 + l15;                                       \
        _Pragma("unroll")                                                     \
        for (int ks = 0; ks < 2; ++ks) {                                      \
            half8 kf = *(half8*)&KhC[krow * HD +                              \
                                     (((ks * 4 + lg) ^ (krow & 7)) * 8)];     \
            _Pragma("unroll")                                                 \
            for (int rt = 0; rt < 2; ++rt)                                    \
                sc[rt][ct] = __builtin_amdgcn_mfma_f32_16x16x32_f16(          \
                    kf, qf[rt][ks], sc[rt][ct], 0, 0, 0);                     \
        }                                                                     \
    }                                                                         \
    __builtin_amdgcn_s_setprio(0);                                            \
    _Pragma("unroll")                                                         \
    for (int rt = 0; rt < 2; ++rt) {                                          \
        float mc_[4];                                                         \
        _Pragma("unroll")                                                     \
        for (int ct = 0; ct < 4; ++ct)                                        \
            mc_[ct] = fmaxf(fmaxf(sc[rt][ct][0], sc[rt][ct][1]),              \
                            fmaxf(sc[rt][ct][2], sc[rt][ct][3]));             \
        float mt = fmaxf(fmaxf(mc_[0], mc_[1]), fmaxf(mc_[2], mc_[3]));       \
        mt = fmaxf(mt, __shfl_xor(mt, 16));                                   \
        mt = fmaxf(mt, __shfl_xor(mt, 32));                                   \
        const float mtc = mt * CSC;                                           \
        if (__any(mtc - mrun[rt] > 8.0f)) {                                   \
            const float mn = fmaxf(mrun[rt], mtc);                            \
            const float alpha = exp2f(mrun[rt] - mn);                         \
            mrun[rt] = mn;                                                    \
            lrun[rt] *= alpha;                                                \
            _Pragma("unroll")                                                 \
            for (int dct = 0; dct < 4; ++dct)                                 \
                _Pragma("unroll")                                             \
                for (int r = 0; r < 4; ++r) oacc[rt][dct][r] *= alpha;        \
        }                                                                     \
        const float mn_ = mrun[rt];                                           \
        float pv_[4][4];                                                      \
        float ls = 0.f;                                                       \
        _Pragma("unroll")                                                     \
        for (int ct = 0; ct < 4; ++ct)                                        \
            _Pragma("unroll")                                                 \
            for (int r = 0; r < 4; ++r) {                                     \
                pv_[ct][r] = exp2f(fmaf(sc[rt][ct][r], CSC, -mn_));           \
                ls += pv_[ct][r];                                             \
            }                                                                 \
        ls += __shfl_xor(ls, 16);                                             \
        ls += __shfl_xor(ls, 32);                                             \
        lrun[rt] += ls;                                                       \
        const int prow_ = pbase + (rt * 16 + l15) * KVBLK;                    \
        _Pragma("unroll")                                                     \
        for (int ct = 0; ct < 4; ++ct) {                                      \
            u32 w01 = __builtin_bit_cast(u32,                                 \
                __builtin_amdgcn_cvt_pkrtz(pv_[ct][0], pv_[ct][1]));          \
            u32 w23 = __builtin_bit_cast(u32,                                 \
                __builtin_amdgcn_cvt_pkrtz(pv_[ct][2], pv_[ct][3]));          \
            *(u32x2*)&Pl[prow_ + ((4 * ct + lg) ^ l15) * 4] =                 \
                (u32x2){w01, w23};                                            \
        }                                                                     \
    }                                                                         \
    __builtin_amdgcn_s_setprio(1);                                            \
    _Pragma("unroll")                                                         \
    for (int ks2 = 0; ks2 < 2; ++ks2) {                                       \
        half8 pa[2];                                                          \
        _Pragma("unroll")                                                     \
        for (int rt = 0; rt < 2; ++rt) {                                      \
            const int prow_ = pbase + (rt * 16 + l15) * KVBLK;                \
            half4 plA_ = *(half4*)&Pl[prow_ + ((8 * ks2 + 2 * lg)     ^ l15) * 4]; \
            half4 plB_ = *(half4*)&Pl[prow_ + ((8 * ks2 + 2 * lg + 1) ^ l15) * 4]; \
            pa[rt] = __builtin_shufflevector(plA_, plB_, 0,1,2,3,4,5,6,7);    \
        }                                                                     \
        _Pragma("unroll")                                                     \
        for (int dct = 0; dct < 4; ++dct) {                                   \
            const int d = dct * 16 + l15;                                     \
            half8 vf = *(half8*)&VtC[d * KVBLK +                              \
                        (((ks2 * 4 + lg) ^ (d & 7) ^ (d >> 3)) * 8)];         \
            _Pragma("unroll")                                                 \
            for (int rt = 0; rt < 2; ++rt)                                    \
                oacc[rt][dct] = __builtin_amdgcn_mfma_f32_16x16x32_f16(       \
                    vf, pa[rt], oacc[rt][dct], 0, 0, 0);                      \
        }                                                                     \
    }                                                                         \
    __builtin_amdgcn_s_setprio(0);                                            \
    if (PF) { V_STORE(VtN, va_, vb_); }                                       \
    __syncthreads();                                                          \
} while (0)

__global__ __launch_bounds__(256, 2) void attn_mfma_kernel(
    const f16* __restrict__ qkvh, f16* __restrict__ attnh)
{
    __shared__ f16 Kh0[KVBLK * HD];       // 8 KB
    __shared__ f16 Kh1[KVBLK * HD];       // 8 KB
    __shared__ f16 Vt0[HD * KVBLK];       // 8 KB  [d][k]
    __shared__ f16 Vt1[HD * KVBLK];       // 8 KB
    __shared__ f16 Pl[4 * 32 * KVBLK];    // 16 KB per-wave [q][k]

    const int tid  = threadIdx.x;
    const int lane = tid & 63;
    const int wave = tid >> 6;
    const int l15  = lane & 15;
    const int lg   = lane >> 4;

    const int nq  = SEQ / QBLK;           // 16
    const int cpx = gridDim.x >> 3;
    const int lid = (blockIdx.x & 7) * cpx + (blockIdx.x >> 3);
    const int b   = lid / (NH * nq);
    const int h   = (lid / nq) % NH;
    const int qc  = lid % nq;
    const int q0  = qc * QBLK + wave * 32;
    const size_t bS = (size_t)b * SEQ;

    const int krow_l = lane >> 3;         // 0..7
    const int kschk  = (lane & 7) ^ krow_l;
    const f16* kxsrc = qkvh + bS * D3 + DM + h * HD + kschk * 8;

    const int vp  = tid >> 3;             // 0..31
    const int vd0 = (tid & 7) * 8;
    const f16* vsrc0 = qkvh + (bS + 2 * vp) * D3 + 2 * DM + h * HD + vd0;

    half8 qf[2][2];
#pragma unroll
    for (int rt = 0; rt < 2; ++rt)
#pragma unroll
        for (int ks = 0; ks < 2; ++ks)
            qf[rt][ks] = *(const half8*)&qkvh[(bS + q0 + rt * 16 + l15) * D3 +
                                              h * HD + ks * 32 + lg * 8];

    f32x4 oacc[2][4];   // O^T: oacc[rt][dct][r] = O[q=l15(+16rt)][d=dct*16+4lg+r]
#pragma unroll
    for (int rt = 0; rt < 2; ++rt)
#pragma unroll
        for (int dct = 0; dct < 4; ++dct) oacc[rt][dct] = (f32x4){0.f, 0.f, 0.f, 0.f};

    float mrun[2], lrun[2];
#pragma unroll
    for (int rt = 0; rt < 2; ++rt) { mrun[rt] = -INFINITY; lrun[rt] = 0.f; }

    const int pbase = wave * 32 * KVBLK;

    {
        async_cp16(kxsrc + (size_t)(wave * 16 +     krow_l) * D3, &Kh0[(wave * 16) * HD]);
        async_cp16(kxsrc + (size_t)(wave * 16 + 8 + krow_l) * D3, &Kh0[(wave * 16 + 8) * HD]);
        half8 va_ = *(const half8*)(vsrc0);
        half8 vb_ = *(const half8*)(vsrc0 + D3);
        V_STORE(Vt0, va_, vb_);
        __syncthreads();
    }

    for (int t = 0; t < NTILES; t += 2) {
        ATTN_STEP(Kh0, Vt0, Kh1, Vt1, t, true);
        ATTN_STEP(Kh1, Vt1, Kh0, Vt0, t + 1, (t + 1) < (NTILES - 1));
    }

#pragma unroll
    for (int rt = 0; rt < 2; ++rt) {
        const float inv = 1.f / lrun[rt];
        const int qq = q0 + rt * 16 + l15;
#pragma unroll
        for (int dct = 0; dct < 4; ++dct) {
            half4 o;
#pragma unroll
            for (int r = 0; r < 4; ++r) o[r] = (f16)(oacc[rt][dct][r] * inv);
            *(half4*)&attnh[(bS + qq) * DM + h * HD + dct * 16 + 4 * lg] = o;
        }
    }
}

// ---------------------------------------------------------------------------
extern "C" void kernel_launch(void* const* d_in, const int* in_sizes, int n_in,
                              void* d_out, int out_size, void* d_ws, size_t ws_size,
                              hipStream_t stream) {
    const float* q    = (const float*)d_in[0];
    const float* k    = (const float*)d_in[1];
    const float* v    = (const float*)d_in[2];
    const float* Wqkv = (const float*)d_in[3];
    const float* bqkv = (const float*)d_in[4];
    const float* Wo   = (const float*)d_in[5];
    const float* bo   = (const float*)d_in[6];
    float* out = (float*)d_out;

    char* ws = (char*)d_ws;
    f16* Ain    = (f16*)ws;                        // [4096][3072]
    f16* attn_h = (f16*)ws;                        // [4096][1024] (reuse)
    f16* Wo_h   = (f16*)(ws + 16777216);           // [1024][1024] (reuse)
    f16* Wqkv_h = (f16*)(ws + 25165824);           // [3072][3072]
    f16* qkv_h  = (f16*)(ws + 44040192);           // [4096][3072]

    conv_concat_kernel<<<dim3(3, MROWS), 256, 0, stream>>>(q, k, v, Ain);
    conv_plain_kernel<<<2048, 256, 0, stream>>>(Wqkv, Wqkv_h, D3 * D3 / 4);

    // QKV projection: 8-phase 256^2, grid 16x12 = 192, 512 threads
    gemm8p_f16_kernel<D3, D3><<<dim3((MROWS / 256) * (D3 / 256)), 512, 0, stream>>>(
        Ain, Wqkv_h, bqkv, qkv_h);

    attn_mfma_kernel<<<dim3(BS * NH * (SEQ / QBLK)), 256, 0, stream>>>(qkv_h, attn_h);

    conv_plain_kernel<<<512, 256, 0, stream>>>(Wo, Wo_h, DM * DM / 4);

    // output projection: 64x128 tile, 2 waves, grid 64x8 = 512
    gemm_out_kernel<<<dim3((MROWS / 64) * (DM / 128)), 128, 0, stream>>>(
        attn_h, Wo_h, bo, out);
}